// Round 10
// baseline (264.453 us; speedup 1.0000x reference)
//
#include <hip/hip_runtime.h>
#include <stdint.h>

#define NE 4096
#define FD 512
#define NCELLS 39
#define NPAIRS 8192

typedef __attribute__((ext_vector_type(8))) short short8;
typedef __attribute__((ext_vector_type(8))) unsigned short ushort8;
typedef __attribute__((ext_vector_type(4))) float f32x4;
typedef __attribute__((ext_vector_type(2))) unsigned int uint2v;

__device__ __forceinline__ unsigned short f2bf(float f) {
  union { float f; uint32_t u; } v; v.f = f;
  uint32_t u = v.u;
  return (unsigned short)((u + 0x7fffu + ((u >> 16) & 1u)) >> 16);  // RNE
}

__device__ __forceinline__ void async16(const void* g, void* l) {
  __builtin_amdgcn_global_load_lds((const __attribute__((address_space(1))) void*)g,
                                   (__attribute__((address_space(3))) void*)l, 16, 0, 0);
}

// ---- kernel 1: embedding fp32 -> bf16 ----
__global__ __launch_bounds__(256) void conv_e(const float* __restrict__ E,
                                              unsigned short* __restrict__ Ebf) {
  const int i = blockIdx.x * 256 + threadIdx.x;
  const float4 v = ((const float4*)E)[i];
  ushort4 o;
  o.x = f2bf(v.x); o.y = f2bf(v.y); o.z = f2bf(v.z); o.w = f2bf(v.w);
  ((ushort4*)Ebf)[i] = o;
}

// ---- kernel 2: Wt[ci][k][n] = wl[c,n] * wl[c,k] * W[n,k], bf16, transposed ----
__global__ __launch_bounds__(256) void prep_w(const float* __restrict__ W,
                                              const float* __restrict__ wl,
                                              unsigned short* __restrict__ Wt,
                                              int c0) {
  __shared__ float tile[32][33];
  const int ci = blockIdx.z;
  const int tn = blockIdx.x * 32, tk = blockIdx.y * 32;
  const int tx = threadIdx.x & 31, ty = threadIdx.x >> 5;
  const float* wlr = wl + (size_t)(c0 + ci) * FD;
#pragma unroll
  for (int i = 0; i < 4; i++) {
    int n = tn + ty + i * 8;
    tile[ty + i * 8][tx] = W[(size_t)n * FD + tk + tx] * wlr[n];
  }
  __syncthreads();
  unsigned short* dst = Wt + (size_t)ci * FD * FD;
#pragma unroll
  for (int i = 0; i < 4; i++) {
    int kout = tk + ty + i * 8;
    dst[(size_t)kout * FD + tn + tx] = f2bf(tile[tx][ty + i * 8] * wlr[kout]);
  }
}

// ---- kernel 3: U[ci][e][k] = sum_n Ebf[e,n] * Wt[ci][k][n]  (bf16 out) ----
// 128x128 tile, BK=32, 4 waves (2x2), 4x4 MFMA 16x16x32 per wave.
// Operands SWAPPED in the MFMA (bq first): D gets M=k-dim, N=entity-dim, so the
// C/D layout (col=lane&15, row=(lane>>4)*4+reg) puts each lane's 4 regs at
// consecutive k -> one packed 8B store per tile instead of 4 scattered 2B stores.
__global__ __launch_bounds__(256) void gemm_k(const unsigned short* __restrict__ Ebf,
                                              const unsigned short* __restrict__ Wt,
                                              unsigned short* __restrict__ U) {
  __shared__ unsigned short As[128 * 32];
  __shared__ unsigned short Bs[128 * 32];
  const int t = threadIdx.x;
  const int ci = blockIdx.z;
  const unsigned short* Ag = Ebf + (size_t)blockIdx.x * 128 * FD;
  const unsigned short* Bg = Wt + (size_t)ci * FD * FD + (size_t)blockIdx.y * 128 * FD;

  f32x4 acc[4][4];
#pragma unroll
  for (int i = 0; i < 4; i++)
#pragma unroll
    for (int j = 0; j < 4; j++) acc[i][j] = (f32x4){0.f, 0.f, 0.f, 0.f};

  const int wave = t >> 6, lane = t & 63;
  const int wm = (wave & 1) * 64, wn = (wave >> 1) * 64;
  const int lr = lane & 15, lq = lane >> 4;
  const int idx0 = t, idx1 = 256 + t;
  const int r0 = idx0 >> 2, cb0 = (idx0 & 3) * 8;
  const int r1 = idx1 >> 2, cb1 = (idx1 & 3) * 8;

  for (int k0 = 0; k0 < FD; k0 += 32) {
    async16(Ag + (size_t)r0 * FD + k0 + cb0, &As[idx0 * 8]);
    async16(Ag + (size_t)r1 * FD + k0 + cb1, &As[idx1 * 8]);
    async16(Bg + (size_t)r0 * FD + k0 + cb0, &Bs[idx0 * 8]);
    async16(Bg + (size_t)r1 * FD + k0 + cb1, &Bs[idx1 * 8]);
    __syncthreads();
    short8 af[4], bq[4];
#pragma unroll
    for (int mi = 0; mi < 4; mi++) af[mi] = *(const short8*)&As[(wm + mi * 16 + lr) * 32 + lq * 8];
#pragma unroll
    for (int ni = 0; ni < 4; ni++) bq[ni] = *(const short8*)&Bs[(wn + ni * 16 + lr) * 32 + lq * 8];
#pragma unroll
    for (int mi = 0; mi < 4; mi++)
#pragma unroll
      for (int ni = 0; ni < 4; ni++)
        acc[mi][ni] = __builtin_amdgcn_mfma_f32_16x16x32_bf16(bq[ni], af[mi], acc[mi][ni], 0, 0, 0);
    __syncthreads();
  }

  // epilogue: D^T layout -> lane holds entity e = ebase + (lane&15),
  // k = kbase + (lane>>4)*4 + r (r=0..3 contiguous). Pack 4 bf16 -> 8B store.
  unsigned short* Up = U + (size_t)ci * NE * FD;
#pragma unroll
  for (int mi = 0; mi < 4; mi++) {
    const int e = blockIdx.x * 128 + wm + mi * 16 + lr;
#pragma unroll
    for (int ni = 0; ni < 4; ni++) {
      const int k = blockIdx.y * 128 + wn + ni * 16 + lq * 4;
      uint2v pk;
      pk.x = (uint32_t)f2bf(acc[mi][ni][0]) | ((uint32_t)f2bf(acc[mi][ni][1]) << 16);
      pk.y = (uint32_t)f2bf(acc[mi][ni][2]) | ((uint32_t)f2bf(acc[mi][ni][3]) << 16);
      *(uint2v*)(Up + (size_t)e * FD + k) = pk;
    }
  }
}

// ---- kernel 4: pair dots via MFMA diagonal ----
// Wave handles 16 pairs. A-frag rows = U[i0[m]], B-frag rows = Ebf[i1[n]];
// C = A·B^T over K=512 (16 MFMA); diagonal C[m][m] = out.
__global__ __launch_bounds__(256) void dot_m(const unsigned short* __restrict__ U,
                                             const unsigned short* __restrict__ Ebf,
                                             const int* __restrict__ index,
                                             float* __restrict__ out,
                                             int c0) {
  const int ci = blockIdx.y;
  const int cg = c0 + ci;
  const int wave = threadIdx.x >> 6, lane = threadIdx.x & 63;
  const int m = lane & 15, kg = lane >> 4;
  const size_t cp = (size_t)cg * NPAIRS;
  const int jb = (blockIdx.x * 4 + wave) * 16;

  const int2 id = ((const int2*)index)[cp + jb + m];
  const unsigned short* ar = U + (size_t)ci * NE * FD + (size_t)id.x * FD + kg * 8;
  const unsigned short* br = Ebf + (size_t)id.y * FD + kg * 8;

  f32x4 acc = (f32x4){0.f, 0.f, 0.f, 0.f};
#pragma unroll
  for (int s = 0; s < 16; s++) {
    const short8 a = *(const short8*)(ar + s * 32);
    const short8 b = *(const short8*)(br + s * 32);
    acc = __builtin_amdgcn_mfma_f32_16x16x32_bf16(a, b, acc, 0, 0, 0);
  }
  const int r = m - kg * 4;
  if (r >= 0 && r < 4) out[cp + jb + m] = acc[r];
}

// ---- fallback (tiny workspace): direct fp32, slow but correct ----
__global__ __launch_bounds__(256) void naive_k(const float* __restrict__ emb,
                                               const int* __restrict__ index,
                                               const float* __restrict__ W,
                                               const float* __restrict__ wl,
                                               float* __restrict__ out) {
  __shared__ float bs[FD];
  __shared__ float red[256];
  const int c = blockIdx.y, p = blockIdx.x;
  const int i0 = index[((size_t)c * NPAIRS + p) * 2];
  const int i1 = index[((size_t)c * NPAIRS + p) * 2 + 1];
  const float* wlc = wl + (size_t)c * FD;
  for (int k = threadIdx.x; k < FD; k += 256) bs[k] = emb[(size_t)i1 * FD + k] * wlc[k];
  __syncthreads();
  float s = 0.f;
  for (int n = threadIdx.x; n < FD; n += 256) {
    const float* wr = W + (size_t)n * FD;
    float tacc = 0.f;
    for (int k = 0; k < FD; k++) tacc += wr[k] * bs[k];
    s += tacc * emb[(size_t)i0 * FD + n] * wlc[n];
  }
  red[threadIdx.x] = s;
  __syncthreads();
  for (int st = 128; st > 0; st >>= 1) {
    if (threadIdx.x < st) red[threadIdx.x] += red[threadIdx.x + st];
    __syncthreads();
  }
  if (threadIdx.x == 0) out[(size_t)c * NPAIRS + p] = red[0];
}

extern "C" void kernel_launch(void* const* d_in, const int* in_sizes, int n_in,
                              void* d_out, int out_size, void* d_ws, size_t ws_size,
                              hipStream_t stream) {
  const float* emb = (const float*)d_in[0];
  const int* index = (const int*)d_in[1];
  const float* Wg = (const float*)d_in[2];
  const float* wl = (const float*)d_in[3];
  float* out = (float*)d_out;

  const size_t ebytes = (size_t)NE * FD * 2;  // 4 MiB bf16 embedding
  const size_t wtcell = (size_t)FD * FD * 2;  // 0.5 MiB per-cell Wt
  const size_t ucell = (size_t)NE * FD * 2;   // 4 MiB per-cell U
  size_t avail = ws_size > ebytes ? ws_size - ebytes : 0;
  int G = (int)(avail / (wtcell + ucell));
  if (G > NCELLS) G = NCELLS;

  if (G < 1) {
    naive_k<<<dim3(NPAIRS, NCELLS), 256, 0, stream>>>(emb, index, Wg, wl, out);
    return;
  }

  unsigned short* Ebf = (unsigned short*)d_ws;
  unsigned short* Wt = (unsigned short*)((char*)d_ws + ebytes);
  unsigned short* U = (unsigned short*)((char*)d_ws + ebytes + (size_t)G * wtcell);

  conv_e<<<dim3((NE * FD / 4) / 256), 256, 0, stream>>>(emb, Ebf);
  for (int c0 = 0; c0 < NCELLS; c0 += G) {
    int g = (NCELLS - c0 < G) ? (NCELLS - c0) : G;
    prep_w<<<dim3(FD / 32, FD / 32, g), 256, 0, stream>>>(Wg, wl, Wt, c0);
    gemm_k<<<dim3(NE / 128, FD / 128, g), 256, 0, stream>>>(Ebf, Wt, U);
    dot_m<<<dim3(NPAIRS / 64, g), 256, 0, stream>>>(U, Ebf, index, out, c0);
  }
}

// Round 11
// 244.173 us; speedup vs baseline: 1.0831x; 1.0831x over previous
//
#include <hip/hip_runtime.h>
#include <stdint.h>

#define NE 4096
#define FD 512
#define NCELLS 39
#define NPAIRS 8192

typedef __attribute__((ext_vector_type(8))) short short8;
typedef __attribute__((ext_vector_type(8))) unsigned short ushort8;
typedef __attribute__((ext_vector_type(4))) float f32x4;

__device__ __forceinline__ unsigned short f2bf(float f) {
  union { float f; uint32_t u; } v; v.f = f;
  uint32_t u = v.u;
  return (unsigned short)((u + 0x7fffu + ((u >> 16) & 1u)) >> 16);  // RNE
}

__device__ __forceinline__ void async16(const void* g, void* l) {
  __builtin_amdgcn_global_load_lds((const __attribute__((address_space(1))) void*)g,
                                   (__attribute__((address_space(3))) void*)l, 16, 0, 0);
}

// ---- kernel 1: embedding fp32 -> bf16 ----
__global__ __launch_bounds__(256) void conv_e(const float* __restrict__ E,
                                              unsigned short* __restrict__ Ebf) {
  const int i = blockIdx.x * 256 + threadIdx.x;
  const float4 v = ((const float4*)E)[i];
  ushort4 o;
  o.x = f2bf(v.x); o.y = f2bf(v.y); o.z = f2bf(v.z); o.w = f2bf(v.w);
  ((ushort4*)Ebf)[i] = o;
}

// ---- kernel 2: Wt[ci][k][n] = wl[c,n] * wl[c,k] * W[n,k], bf16, transposed ----
__global__ __launch_bounds__(256) void prep_w(const float* __restrict__ W,
                                              const float* __restrict__ wl,
                                              unsigned short* __restrict__ Wt,
                                              int c0) {
  __shared__ float tile[32][33];
  const int ci = blockIdx.z;
  const int tn = blockIdx.x * 32, tk = blockIdx.y * 32;
  const int tx = threadIdx.x & 31, ty = threadIdx.x >> 5;
  const float* wlr = wl + (size_t)(c0 + ci) * FD;
#pragma unroll
  for (int i = 0; i < 4; i++) {
    int n = tn + ty + i * 8;
    tile[ty + i * 8][tx] = W[(size_t)n * FD + tk + tx] * wlr[n];
  }
  __syncthreads();
  unsigned short* dst = Wt + (size_t)ci * FD * FD;
#pragma unroll
  for (int i = 0; i < 4; i++) {
    int kout = tk + ty + i * 8;
    dst[(size_t)kout * FD + tn + tx] = f2bf(tile[tx][ty + i * 8] * wlr[kout]);
  }
}

// ---- kernel 3: U[ci][e][k] = sum_n Ebf[e,n] * Wt[ci][k][n]  (bf16 out) ----
// 128x128 tile, BK=64 staged as TWO stacked BK=32 sub-tiles (keeps the
// lane-contiguous global_load_lds layout and the benign 32-short row stride).
// 8 barrier pairs instead of 16; 32 MFMA per barrier.
__global__ __launch_bounds__(256) void gemm_k(const unsigned short* __restrict__ Ebf,
                                              const unsigned short* __restrict__ Wt,
                                              unsigned short* __restrict__ U) {
  __shared__ unsigned short As[2 * 128 * 32];  // 16 KB
  __shared__ unsigned short Bs[2 * 128 * 32];  // 16 KB
  const int t = threadIdx.x;
  const int ci = blockIdx.z;
  const unsigned short* Ag = Ebf + (size_t)blockIdx.x * 128 * FD;
  const unsigned short* Bg = Wt + (size_t)ci * FD * FD + (size_t)blockIdx.y * 128 * FD;

  f32x4 acc[4][4];
#pragma unroll
  for (int i = 0; i < 4; i++)
#pragma unroll
    for (int j = 0; j < 4; j++) acc[i][j] = (f32x4){0.f, 0.f, 0.f, 0.f};

  const int wave = t >> 6, lane = t & 63;
  const int wm = (wave & 1) * 64, wn = (wave >> 1) * 64;
  const int lr = lane & 15, lq = lane >> 4;

  // staging map: 16B chunk c in [0,1024): subtile h=c>>9, row r=(c>>2)&127,
  // quarter j=c&3.  LDS dest (shorts) = c*8 (linear, lane-contiguous).
  // src (shorts) = r*FD + k0 + h*32 + j*8.
  int soff[4], doff[4];
#pragma unroll
  for (int p = 0; p < 4; p++) {
    const int c = p * 256 + t;
    const int h = c >> 9, r = (c >> 2) & 127, j = c & 3;
    soff[p] = r * FD + h * 32 + j * 8;
    doff[p] = c * 8;
  }

  for (int k0 = 0; k0 < FD; k0 += 64) {
#pragma unroll
    for (int p = 0; p < 4; p++) async16(Ag + soff[p] + k0, &As[doff[p]]);
#pragma unroll
    for (int p = 0; p < 4; p++) async16(Bg + soff[p] + k0, &Bs[doff[p]]);
    __syncthreads();
#pragma unroll
    for (int kk = 0; kk < 2; kk++) {
      short8 af[4], bq[4];
#pragma unroll
      for (int mi = 0; mi < 4; mi++)
        af[mi] = *(const short8*)&As[kk * 4096 + (wm + mi * 16 + lr) * 32 + lq * 8];
#pragma unroll
      for (int ni = 0; ni < 4; ni++)
        bq[ni] = *(const short8*)&Bs[kk * 4096 + (wn + ni * 16 + lr) * 32 + lq * 8];
#pragma unroll
      for (int mi = 0; mi < 4; mi++)
#pragma unroll
        for (int ni = 0; ni < 4; ni++)
          acc[mi][ni] = __builtin_amdgcn_mfma_f32_16x16x32_bf16(af[mi], bq[ni], acc[mi][ni], 0, 0, 0);
    }
    __syncthreads();
  }

  // epilogue (R9 layout): C/D col=lane&15 -> n, row=(lane>>4)*4+r -> entity.
  // 16 consecutive lanes write 32B-contiguous segments.
  unsigned short* Up = U + (size_t)ci * NE * FD;
#pragma unroll
  for (int mi = 0; mi < 4; mi++) {
    int mbase = blockIdx.x * 128 + wm + mi * 16 + lq * 4;
#pragma unroll
    for (int ni = 0; ni < 4; ni++) {
      int n = blockIdx.y * 128 + wn + ni * 16 + lr;
#pragma unroll
      for (int r = 0; r < 4; r++) {
        Up[(size_t)(mbase + r) * FD + n] = f2bf(acc[mi][ni][r]);
      }
    }
  }
}

// ---- kernel 4: pair dots via MFMA diagonal ----
// Wave handles 16 pairs. A-frag rows = U[i0[m]], B-frag rows = Ebf[i1[n]];
// C = A·B^T over K=512 (16 MFMA); diagonal C[m][m] = out.
__global__ __launch_bounds__(256) void dot_m(const unsigned short* __restrict__ U,
                                             const unsigned short* __restrict__ Ebf,
                                             const int* __restrict__ index,
                                             float* __restrict__ out,
                                             int c0) {
  const int ci = blockIdx.y;
  const int cg = c0 + ci;
  const int wave = threadIdx.x >> 6, lane = threadIdx.x & 63;
  const int m = lane & 15, kg = lane >> 4;
  const size_t cp = (size_t)cg * NPAIRS;
  const int jb = (blockIdx.x * 4 + wave) * 16;

  const int2 id = ((const int2*)index)[cp + jb + m];
  const unsigned short* ar = U + (size_t)ci * NE * FD + (size_t)id.x * FD + kg * 8;
  const unsigned short* br = Ebf + (size_t)id.y * FD + kg * 8;

  f32x4 acc = (f32x4){0.f, 0.f, 0.f, 0.f};
#pragma unroll
  for (int s = 0; s < 16; s++) {
    const short8 a = *(const short8*)(ar + s * 32);
    const short8 b = *(const short8*)(br + s * 32);
    acc = __builtin_amdgcn_mfma_f32_16x16x32_bf16(a, b, acc, 0, 0, 0);
  }
  const int r = m - kg * 4;
  if (r >= 0 && r < 4) out[cp + jb + m] = acc[r];
}

// ---- fallback (tiny workspace): direct fp32, slow but correct ----
__global__ __launch_bounds__(256) void naive_k(const float* __restrict__ emb,
                                               const int* __restrict__ index,
                                               const float* __restrict__ W,
                                               const float* __restrict__ wl,
                                               float* __restrict__ out) {
  __shared__ float bs[FD];
  __shared__ float red[256];
  const int c = blockIdx.y, p = blockIdx.x;
  const int i0 = index[((size_t)c * NPAIRS + p) * 2];
  const int i1 = index[((size_t)c * NPAIRS + p) * 2 + 1];
  const float* wlc = wl + (size_t)c * FD;
  for (int k = threadIdx.x; k < FD; k += 256) bs[k] = emb[(size_t)i1 * FD + k] * wlc[k];
  __syncthreads();
  float s = 0.f;
  for (int n = threadIdx.x; n < FD; n += 256) {
    const float* wr = W + (size_t)n * FD;
    float tacc = 0.f;
    for (int k = 0; k < FD; k++) tacc += wr[k] * bs[k];
    s += tacc * emb[(size_t)i0 * FD + n] * wlc[n];
  }
  red[threadIdx.x] = s;
  __syncthreads();
  for (int st = 128; st > 0; st >>= 1) {
    if (threadIdx.x < st) red[threadIdx.x] += red[threadIdx.x + st];
    __syncthreads();
  }
  if (threadIdx.x == 0) out[(size_t)c * NPAIRS + p] = red[0];
}

extern "C" void kernel_launch(void* const* d_in, const int* in_sizes, int n_in,
                              void* d_out, int out_size, void* d_ws, size_t ws_size,
                              hipStream_t stream) {
  const float* emb = (const float*)d_in[0];
  const int* index = (const int*)d_in[1];
  const float* Wg = (const float*)d_in[2];
  const float* wl = (const float*)d_in[3];
  float* out = (float*)d_out;

  const size_t ebytes = (size_t)NE * FD * 2;  // 4 MiB bf16 embedding
  const size_t wtcell = (size_t)FD * FD * 2;  // 0.5 MiB per-cell Wt
  const size_t ucell = (size_t)NE * FD * 2;   // 4 MiB per-cell U
  size_t avail = ws_size > ebytes ? ws_size - ebytes : 0;
  int G = (int)(avail / (wtcell + ucell));
  if (G > NCELLS) G = NCELLS;

  if (G < 1) {
    naive_k<<<dim3(NPAIRS, NCELLS), 256, 0, stream>>>(emb, index, Wg, wl, out);
    return;
  }

  unsigned short* Ebf = (unsigned short*)d_ws;
  unsigned short* Wt = (unsigned short*)((char*)d_ws + ebytes);
  unsigned short* U = (unsigned short*)((char*)d_ws + ebytes + (size_t)G * wtcell);

  conv_e<<<dim3((NE * FD / 4) / 256), 256, 0, stream>>>(emb, Ebf);
  for (int c0 = 0; c0 < NCELLS; c0 += G) {
    int g = (NCELLS - c0 < G) ? (NCELLS - c0) : G;
    prep_w<<<dim3(FD / 32, FD / 32, g), 256, 0, stream>>>(Wg, wl, Wt, c0);
    gemm_k<<<dim3(NE / 128, FD / 128, g), 256, 0, stream>>>(Ebf, Wt, U);
    dot_m<<<dim3(NPAIRS / 64, g), 256, 0, stream>>>(U, Ebf, index, out, c0);
  }
}